// Round 13
// baseline (134.562 us; speedup 1.0000x reference)
//
#include <hip/hip_runtime.h>

#define L_SEQ 4096
#define DMODEL 768
#define NH 12
#define DK 64

typedef __bf16 bf16;
typedef __bf16 bf16x8 __attribute__((ext_vector_type(8)));
typedef __bf16 bf16x4 __attribute__((ext_vector_type(4)));
typedef float f32x4 __attribute__((ext_vector_type(4)));

#define QSCALE 0.1803368801111204f  /* 0.125 * log2(e): exp2 domain */
#define DEFER_THR 8.0f              /* defer-max threshold (exp2 domain): P <= 2^8 */

__device__ __forceinline__ void gload16(const void* g, void* l) {
    __builtin_amdgcn_global_load_lds(
        (const __attribute__((address_space(1))) unsigned int*)g,
        (__attribute__((address_space(3))) unsigned int*)l, 16, 0, 0);
}

// -------------------- Kernel 0: prep --------------------
__global__ __launch_bounds__(256) void prep_kernel(
    const float* __restrict__ x,
    const float* __restrict__ w_q, const float* __restrict__ w_k,
    const float* __restrict__ w_v, const float* __restrict__ w_o,
    bf16* __restrict__ xb, bf16* __restrict__ wqt, bf16* __restrict__ wkt,
    bf16* __restrict__ wvt, bf16* __restrict__ wot)
{
    const int bid = blockIdx.x;
    const int t = threadIdx.x;
    if (bid < 576) {
        __shared__ bf16 Ls[64][72];
        const int mat = bid / 144;
        const int tile = bid % 144;
        const int k0 = (tile / 12) * 64;
        const int c0 = (tile % 12) * 64;
        const float* W = mat == 0 ? w_q : mat == 1 ? w_k : mat == 2 ? w_v : w_o;
        bf16* WT = mat == 0 ? wqt : mat == 1 ? wkt : mat == 2 ? wvt : wot;
        #pragma unroll
        for (int p = 0; p < 4; ++p) {
            int id = t + p * 256;
            int r = id >> 4, c4 = id & 15;
            float4 v = *(const float4*)(W + (size_t)(k0 + r) * DMODEL + c0 + c4 * 4);
            bf16x4 b; b[0] = (bf16)v.x; b[1] = (bf16)v.y; b[2] = (bf16)v.z; b[3] = (bf16)v.w;
            *(bf16x4*)&Ls[r][c4 * 4] = b;
        }
        __syncthreads();
        #pragma unroll
        for (int p = 0; p < 2; ++p) {
            int id = t + p * 256;
            int crow = id >> 3, kc = id & 7;
            bf16x8 o;
            #pragma unroll
            for (int e = 0; e < 8; ++e) o[e] = Ls[kc * 8 + e][crow];
            *(bf16x8*)(WT + (size_t)(c0 + crow) * DMODEL + k0 + kc * 8) = o;
        }
    } else {
        const size_t base = (size_t)(bid - 576) * 4096;
        #pragma unroll
        for (int p = 0; p < 4; ++p) {
            size_t idx = base + (size_t)(t + p * 256) * 4;
            float4 v = *(const float4*)(x + idx);
            bf16x4 b; b[0] = (bf16)v.x; b[1] = (bf16)v.y; b[2] = (bf16)v.z; b[3] = (bf16)v.w;
            *(bf16x4*)(xb + idx) = b;
        }
    }
}

// -------------------- Kernel A: fused Q/K/V projections (r9) ----------
__global__ __launch_bounds__(256) void proj_kernel(
    const bf16* __restrict__ xb,
    const bf16* __restrict__ wqt, const bf16* __restrict__ wkt, const bf16* __restrict__ wvt,
    const float* __restrict__ b_q, const float* __restrict__ b_k, const float* __restrict__ b_v,
    bf16* __restrict__ qbuf, bf16* __restrict__ kbuf, bf16* __restrict__ vt)
{
    __shared__ bf16 As[128][72];
    __shared__ bf16 Bs[64][72];
    const int t = threadIdx.x;
    const int w = t >> 6, l = t & 63;
    const int lg = l >> 4, lr = l & 15;

    if (blockIdx.x < 768) {
        const int bn = blockIdx.x % 24;
        const int bm = blockIdx.x / 24;
        const int m0 = bm * 128;
        const int gn0 = bn * 64;
        const int sel = gn0 / DMODEL;        // 0=Q, 1=K
        const int c0 = gn0 % DMODEL;
        const bf16* WT = sel ? wkt : wqt;
        const float* bias = sel ? b_k : b_q;
        const float scale = sel ? 1.0f : QSCALE;

        f32x4 acc[2][4];
        #pragma unroll
        for (int i = 0; i < 2; i++)
            #pragma unroll
            for (int j = 0; j < 4; j++) acc[i][j] = (f32x4){0.f, 0.f, 0.f, 0.f};

        for (int kk = 0; kk < DMODEL; kk += 64) {
            #pragma unroll
            for (int p = 0; p < 4; ++p) {
                int id = t + p * 256;
                int row = id >> 3, ch = id & 7;
                *(bf16x8*)&As[row][ch * 8] =
                    *(const bf16x8*)(xb + (size_t)(m0 + row) * DMODEL + kk + ch * 8);
            }
            #pragma unroll
            for (int p = 0; p < 2; ++p) {
                int id = t + p * 256;
                int n = id >> 3, ch = id & 7;
                *(bf16x8*)&Bs[n][ch * 8] =
                    *(const bf16x8*)(WT + (size_t)(c0 + n) * DMODEL + kk + ch * 8);
            }
            __syncthreads();
            #pragma unroll
            for (int ks = 0; ks < 2; ++ks) {
                bf16x8 a[2], bfr[4];
                #pragma unroll
                for (int i = 0; i < 2; i++) a[i] = *(const bf16x8*)&As[w * 32 + i * 16 + lr][ks * 32 + lg * 8];
                #pragma unroll
                for (int j = 0; j < 4; j++) bfr[j] = *(const bf16x8*)&Bs[j * 16 + lr][ks * 32 + lg * 8];
                #pragma unroll
                for (int i = 0; i < 2; i++)
                    #pragma unroll
                    for (int j = 0; j < 4; j++)
                        acc[i][j] = __builtin_amdgcn_mfma_f32_16x16x32_bf16(a[i], bfr[j], acc[i][j], 0, 0, 0);
            }
            __syncthreads();
        }
        #pragma unroll
        for (int i = 0; i < 2; i++) {
            #pragma unroll
            for (int j = 0; j < 4; j++) {
                int c = c0 + j * 16 + lr;
                int h = c >> 6, d = c & 63;
                float bb = bias[c];
                #pragma unroll
                for (int r = 0; r < 4; r++) {
                    int m = m0 + w * 32 + i * 16 + lg * 4 + r;
                    float v = (acc[i][j][r] + bb) * scale;
                    if (sel == 0) {
                        qbuf[((size_t)h * L_SEQ + m) * DK + d] = (bf16)v;
                    } else {
                        size_t idx = (size_t)h * L_SEQ * DK + (size_t)(m >> 6) * 4096
                                   + (size_t)(m & 63) * 64 + (((d >> 3) ^ (m & 7)) << 3) + (d & 7);
                        kbuf[idx] = (bf16)v;
                    }
                }
            }
        }
    } else {
        const int bid = blockIdx.x - 768;
        const int bc = bid % 12;
        const int bmm = bid / 12;
        const int c0 = bc * 64;
        const int mm0 = bmm * 128;

        f32x4 acc[8];
        #pragma unroll
        for (int j = 0; j < 8; j++) acc[j] = (f32x4){0.f, 0.f, 0.f, 0.f};

        for (int kk = 0; kk < DMODEL; kk += 64) {
            #pragma unroll
            for (int p = 0; p < 4; ++p) {
                int id = t + p * 256;
                int row = id >> 3, ch = id & 7;
                *(bf16x8*)&As[row][ch * 8] =
                    *(const bf16x8*)(xb + (size_t)(mm0 + row) * DMODEL + kk + ch * 8);
            }
            #pragma unroll
            for (int p = 0; p < 2; ++p) {
                int id = t + p * 256;
                int n = id >> 3, ch = id & 7;
                *(bf16x8*)&Bs[n][ch * 8] =
                    *(const bf16x8*)(wvt + (size_t)(c0 + n) * DMODEL + kk + ch * 8);
            }
            __syncthreads();
            #pragma unroll
            for (int ks = 0; ks < 2; ++ks) {
                bf16x8 a = *(const bf16x8*)&Bs[w * 16 + lr][ks * 32 + lg * 8];
                #pragma unroll
                for (int j = 0; j < 8; j++) {
                    bf16x8 b = *(const bf16x8*)&As[j * 16 + lr][ks * 32 + lg * 8];
                    acc[j] = __builtin_amdgcn_mfma_f32_16x16x32_bf16(a, b, acc[j], 0, 0, 0);
                }
            }
            __syncthreads();
        }
        #pragma unroll
        for (int j = 0; j < 8; j++) {
            int m = mm0 + j * 16 + lr;
            #pragma unroll
            for (int r = 0; r < 4; r++) {
                int c = c0 + w * 16 + lg * 4 + r;
                float v = acc[j][r] + b_v[c];
                size_t idx = (size_t)(c >> 6) * DK * L_SEQ + (size_t)(m >> 6) * 4096
                           + (size_t)(c & 63) * 64 + ((((m >> 3) & 7) ^ (c & 7)) << 3) + (m & 7);
                vt[idx] = (bf16)v;
            }
        }
    }
}

// -------------------- Kernel B: causal flash attention (QBLK=128) ----------
// 8 waves share one kv tile (wave w owns q-rows 16w..16w+15 of a 128-row
// q-block). LDS 32KB (dbuf K+V) -> 4 blocks/CU. No merge phase: denominator
// is lane-local (acc_sum same D-layout as acc).
__global__ __launch_bounds__(512) void attn_kernel(
    const bf16* __restrict__ qbuf, const bf16* __restrict__ kbuf,
    const bf16* __restrict__ vt, bf16* __restrict__ obuf)
{
    __shared__ __align__(16) char lds[32768];
    // K bufs: b*8192 @ [0,16384); V bufs: 16384 + b*8192

    const int bid = blockIdx.x;
    const int h  = bid % NH;
    const int qt = 31 - bid / NH;         // 128-row q tile, heavy first (LPT)
    const int q0 = qt * 128;
    const int nt = 2 * (qt + 1);          // causal kv tiles of 64

    const int t = threadIdx.x;
    const int w = t >> 6;                 // wave 0..7 -> q rows 16w..16w+15
    const int l = t & 63;
    const int lg = l >> 4, lr = l & 15;
    const int sw = (lr & 7) << 4;

    const size_t qrow = (size_t)h * L_SEQ + q0 + w * 16 + lr;
    const bf16x8 qa0 = *(const bf16x8*)(qbuf + qrow * DK + 0  + lg * 8);
    const bf16x8 qa1 = *(const bf16x8*)(qbuf + qrow * DK + 32 + lg * 8);

    bf16x8 ones;
    #pragma unroll
    for (int e = 0; e < 8; ++e) ones[e] = (bf16)1.0f;

    f32x4 acc[4];
    #pragma unroll
    for (int j = 0; j < 4; j++) acc[j] = (f32x4){0.f, 0.f, 0.f, 0.f};
    f32x4 acc_sum = (f32x4){0.f, 0.f, 0.f, 0.f};   // row sums, same layout as acc
    float run_m = -1e30f;                           // running max (q = lr)

    const bf16* kb_base = kbuf + (size_t)h * L_SEQ * DK;
    const bf16* vt_base = vt + (size_t)h * DK * L_SEQ;

    // prologue: stage tile 0 into buffer 0 (512 thr x 16B covers 8KB K + 8KB V)
    gload16(kb_base + t * 8, lds + t * 16);
    gload16(vt_base + t * 8, lds + 16384 + t * 16);

    for (int it = 0; it < nt; ++it) {
        const int b = it & 1;
        // wait own DMA for tile `it`, then barrier: all shares landed AND all
        // waves finished reading buffer b (from iteration it-2).
        asm volatile("s_waitcnt vmcnt(0)" ::: "memory");
        __builtin_amdgcn_sched_barrier(0);
        __builtin_amdgcn_s_barrier();
        if (it + 1 < nt) {                // DMA next tile; flies during compute
            const bf16* kg = kb_base + (size_t)(it + 1) * 4096;
            const bf16* vg = vt_base + (size_t)(it + 1) * 4096;
            char* kl = lds + (size_t)(b ^ 1) * 8192;
            char* vl = lds + 16384 + (size_t)(b ^ 1) * 8192;
            gload16(kg + t * 8, kl + t * 16);
            gload16(vg + t * 8, vl + t * 16);
        }
        char* Kbase = lds + (size_t)b * 8192;
        char* Vbase = lds + 16384 + (size_t)b * 8192;
        // S^T = K Q^T : s[j][r] -> kv-local = j*16 + lg*4 + r, q-local = lr
        f32x4 s[4];
        #pragma unroll
        for (int j = 0; j < 4; j++) s[j] = (f32x4){0.f, 0.f, 0.f, 0.f};
        __builtin_amdgcn_s_setprio(1);
        #pragma unroll
        for (int dh = 0; dh < 2; ++dh) {
            const bf16x8 qa = dh ? qa1 : qa0;
            #pragma unroll
            for (int j = 0; j < 4; j++) {
                bf16x8 kb = *(const bf16x8*)(Kbase + (j * 16 + lr) * 128 + ((dh * 64 + lg * 16) ^ sw));
                s[j] = __builtin_amdgcn_mfma_f32_16x16x32_bf16(kb, qa, s[j], 0, 0, 0);
            }
        }
        __builtin_amdgcn_s_setprio(0);
        if (it >= nt - 2) {               // causal mask on the two diagonal tiles
            const int kvrel = (it - (nt - 2)) * 64;   // 0 or 64
            const int qoff = w * 16 + lr;
            #pragma unroll
            for (int j = 0; j < 4; j++)
                #pragma unroll
                for (int r = 0; r < 4; r++)
                    if (kvrel + j * 16 + lg * 4 + r > qoff) s[j][r] = -3e30f;
        }
        // tile max: max3 tree + 2 shfls
        float m0 = fmaxf(fmaxf(s[0][0], s[0][1]), s[0][2]);
        float m1 = fmaxf(fmaxf(s[0][3], s[1][0]), s[1][1]);
        float m2 = fmaxf(fmaxf(s[1][2], s[1][3]), s[2][0]);
        float m3 = fmaxf(fmaxf(s[2][1], s[2][2]), s[2][3]);
        float m4 = fmaxf(fmaxf(s[3][0], s[3][1]), s[3][2]);
        float t1 = fmaxf(fmaxf(m0, m1), m2);
        float t2 = fmaxf(fmaxf(m3, m4), s[3][3]);
        float mx = fmaxf(t1, t2);
        mx = fmaxf(mx, __shfl_xor(mx, 16));
        mx = fmaxf(mx, __shfl_xor(mx, 32));
        // defer-max rescale
        if (!__all(mx <= run_m + DEFER_THR)) {
            const float nm = fmaxf(run_m, mx);
            const float scq = exp2f(run_m - nm);
            run_m = nm;
            float sc0 = __shfl(scq, lg * 4 + 0);
            float sc1 = __shfl(scq, lg * 4 + 1);
            float sc2 = __shfl(scq, lg * 4 + 2);
            float sc3 = __shfl(scq, lg * 4 + 3);
            #pragma unroll
            for (int jd = 0; jd < 4; jd++) {
                acc[jd][0] *= sc0; acc[jd][1] *= sc1;
                acc[jd][2] *= sc2; acc[jd][3] *= sc3;
            }
            acc_sum[0] *= sc0; acc_sum[1] *= sc1;
            acc_sum[2] *= sc2; acc_sum[3] *= sc3;
        }
        // P = 2^(s - run_m) packed to words W[j][hh] (kv pair tp = 8j + 2lg + hh)
        unsigned Wp[4][2];
        #pragma unroll
        for (int j = 0; j < 4; j++) {
            float e0 = exp2f(s[j][0] - run_m);
            float e1 = exp2f(s[j][1] - run_m);
            float e2 = exp2f(s[j][2] - run_m);
            float e3 = exp2f(s[j][3] - run_m);
            asm("v_cvt_pk_bf16_f32 %0, %1, %2" : "=v"(Wp[j][0]) : "v"(e0), "v"(e1));
            asm("v_cvt_pk_bf16_f32 %0, %1, %2" : "=v"(Wp[j][1]) : "v"(e2), "v"(e3));
        }
        // PV + row-sum via K=32 MFMA; P repacked in-register (permlane swaps)
        __builtin_amdgcn_s_setprio(1);
        #pragma unroll
        for (int dh = 0; dh < 2; ++dh) {
            unsigned x0 = Wp[2 * dh][0], y0 = Wp[2 * dh + 1][0];
            unsigned x1 = Wp[2 * dh][1], y1 = Wp[2 * dh + 1][1];
            asm("v_permlane32_swap_b32 %0, %1" : "+v"(x0), "+v"(y0));
            asm("v_permlane16_swap_b32 %0, %1" : "+v"(x0), "+v"(y0));
            asm("v_permlane32_swap_b32 %0, %1" : "+v"(x1), "+v"(y1));
            asm("v_permlane16_swap_b32 %0, %1" : "+v"(x1), "+v"(y1));
            union { unsigned u[4]; bf16x8 v; } pk;
            pk.u[0] = x0; pk.u[1] = x1; pk.u[2] = y0; pk.u[3] = y1;
            const bf16x8 pa = pk.v;
            acc_sum = __builtin_amdgcn_mfma_f32_16x16x32_bf16(pa, ones, acc_sum, 0, 0, 0);
            #pragma unroll
            for (int jd = 0; jd < 4; jd++) {
                bf16x8 vb = *(const bf16x8*)(Vbase + (jd * 16 + lr) * 128 + ((dh * 64 + lg * 16) ^ sw));
                acc[jd] = __builtin_amdgcn_mfma_f32_16x16x32_bf16(pa, vb, acc[jd], 0, 0, 0);
            }
        }
        __builtin_amdgcn_s_setprio(0);
    }

    // epilogue: denominator is lane-local; direct normalized write
    #pragma unroll
    for (int jd = 0; jd < 4; jd++) {
        #pragma unroll
        for (int r = 0; r < 4; r++) {
            int m = q0 + w * 16 + lg * 4 + r;
            obuf[(size_t)m * DMODEL + h * DK + jd * 16 + lr] = (bf16)(acc[jd][r] / acc_sum[r]);
        }
    }
}

// -------------------- Kernel C: output projection (r9) ---
__global__ __launch_bounds__(256) void out_proj_kernel(
    const bf16* __restrict__ obuf, const bf16* __restrict__ wot,
    const float* __restrict__ b_o, float* __restrict__ out)
{
    __shared__ bf16 As[128][72];
    __shared__ bf16 Bts[64][72];
    const int bn = blockIdx.x % 12;
    const int bm = blockIdx.x / 12;
    const int m0 = bm * 128, c0 = bn * 64;
    const int t = threadIdx.x;
    const int w = t >> 6, l = t & 63, lg = l >> 4, lr = l & 15;

    f32x4 acc[2][4];
    #pragma unroll
    for (int i = 0; i < 2; i++)
        #pragma unroll
        for (int j = 0; j < 4; j++) acc[i][j] = (f32x4){0.f, 0.f, 0.f, 0.f};

    for (int kk = 0; kk < DMODEL; kk += 64) {
        #pragma unroll
        for (int p = 0; p < 4; ++p) {
            int id = t + p * 256;
            int row = id >> 3, ch = id & 7;
            *(bf16x8*)&As[row][ch * 8] =
                *(const bf16x8*)(obuf + (size_t)(m0 + row) * DMODEL + kk + ch * 8);
        }
        #pragma unroll
        for (int p = 0; p < 2; ++p) {
            int id = t + p * 256;
            int n = id >> 3, ch = id & 7;
            *(bf16x8*)&Bts[n][ch * 8] =
                *(const bf16x8*)(wot + (size_t)(c0 + n) * DMODEL + kk + ch * 8);
        }
        __syncthreads();
        #pragma unroll
        for (int ks = 0; ks < 2; ++ks) {
            bf16x8 a[2], bfr[4];
            #pragma unroll
            for (int i = 0; i < 2; i++) a[i] = *(const bf16x8*)&As[w * 32 + i * 16 + lr][ks * 32 + lg * 8];
            #pragma unroll
            for (int j = 0; j < 4; j++) bfr[j] = *(const bf16x8*)&Bts[j * 16 + lr][ks * 32 + lg * 8];
            #pragma unroll
            for (int i = 0; i < 2; i++)
                #pragma unroll
                for (int j = 0; j < 4; j++)
                    acc[i][j] = __builtin_amdgcn_mfma_f32_16x16x32_bf16(a[i], bfr[j], acc[i][j], 0, 0, 0);
        }
        __syncthreads();
    }
    #pragma unroll
    for (int i = 0; i < 2; i++) {
        #pragma unroll
        for (int j = 0; j < 4; j++) {
            int c = c0 + j * 16 + lr;
            float bb = b_o[c];
            #pragma unroll
            for (int r = 0; r < 4; r++) {
                int m = m0 + w * 32 + i * 16 + lg * 4 + r;
                out[(size_t)m * DMODEL + c] = acc[i][j][r] + bb;
            }
        }
    }
}

extern "C" void kernel_launch(void* const* d_in, const int* in_sizes, int n_in,
                              void* d_out, int out_size, void* d_ws, size_t ws_size,
                              hipStream_t stream) {
    const float* x   = (const float*)d_in[0];
    const float* w_q = (const float*)d_in[1];
    const float* b_q = (const float*)d_in[2];
    const float* w_k = (const float*)d_in[3];
    const float* b_k = (const float*)d_in[4];
    const float* w_v = (const float*)d_in[5];
    const float* b_v = (const float*)d_in[6];
    const float* w_o = (const float*)d_in[7];
    const float* b_o = (const float*)d_in[8];
    float* out = (float*)d_out;

    char* ws = (char*)d_ws;
    const size_t SZ = (size_t)NH * L_SEQ * DK * sizeof(bf16);   // 6,291,456
    const size_t WTSZ = (size_t)DMODEL * DMODEL * sizeof(bf16); // 1,179,648
    bf16* qbuf = (bf16*)(ws);
    bf16* kbuf = (bf16*)(ws + SZ);
    bf16* vt   = (bf16*)(ws + 2 * SZ);
    bf16* obuf = (bf16*)(ws + 3 * SZ);
    bf16* xb   = (bf16*)(ws + 4 * SZ);
    bf16* wqt  = (bf16*)(ws + 5 * SZ);
    bf16* wkt  = (bf16*)(ws + 5 * SZ + WTSZ);
    bf16* wvt  = (bf16*)(ws + 5 * SZ + 2 * WTSZ);
    bf16* wot  = (bf16*)(ws + 5 * SZ + 3 * WTSZ);

    prep_kernel<<<dim3(1344), dim3(256), 0, stream>>>(x, w_q, w_k, w_v, w_o, xb, wqt, wkt, wvt, wot);
    proj_kernel<<<dim3(1152), dim3(256), 0, stream>>>(xb, wqt, wkt, wvt, b_q, b_k, b_v, qbuf, kbuf, vt);
    attn_kernel<<<dim3(384), dim3(512), 0, stream>>>(qbuf, kbuf, vt, obuf);
    out_proj_kernel<<<dim3(384), dim3(256), 0, stream>>>(obuf, wot, b_o, out);
}

// Round 14
// 120.167 us; speedup vs baseline: 1.1198x; 1.1198x over previous
//
#include <hip/hip_runtime.h>

#define L_SEQ 4096
#define DMODEL 768
#define NH 12
#define DK 64

typedef __bf16 bf16;
typedef __bf16 bf16x8 __attribute__((ext_vector_type(8)));
typedef __bf16 bf16x4 __attribute__((ext_vector_type(4)));
typedef float f32x4 __attribute__((ext_vector_type(4)));

#define QSCALE 0.1803368801111204f  /* 0.125 * log2(e): exp2 domain */
#define DEFER_THR 8.0f              /* defer-max threshold (exp2 domain): P <= 2^8 */

__device__ __forceinline__ void gload16(const void* g, void* l) {
    __builtin_amdgcn_global_load_lds(
        (const __attribute__((address_space(1))) unsigned int*)g,
        (__attribute__((address_space(3))) unsigned int*)l, 16, 0, 0);
}

// -------------------- Kernel 0: prep (r9) --------------------
__global__ __launch_bounds__(256) void prep_kernel(
    const float* __restrict__ x,
    const float* __restrict__ w_q, const float* __restrict__ w_k,
    const float* __restrict__ w_v, const float* __restrict__ w_o,
    bf16* __restrict__ xb, bf16* __restrict__ wqt, bf16* __restrict__ wkt,
    bf16* __restrict__ wvt, bf16* __restrict__ wot)
{
    const int bid = blockIdx.x;
    const int t = threadIdx.x;
    if (bid < 576) {
        __shared__ bf16 Ls[64][72];
        const int mat = bid / 144;
        const int tile = bid % 144;
        const int k0 = (tile / 12) * 64;
        const int c0 = (tile % 12) * 64;
        const float* W = mat == 0 ? w_q : mat == 1 ? w_k : mat == 2 ? w_v : w_o;
        bf16* WT = mat == 0 ? wqt : mat == 1 ? wkt : mat == 2 ? wvt : wot;
        #pragma unroll
        for (int p = 0; p < 4; ++p) {
            int id = t + p * 256;
            int r = id >> 4, c4 = id & 15;
            float4 v = *(const float4*)(W + (size_t)(k0 + r) * DMODEL + c0 + c4 * 4);
            bf16x4 b; b[0] = (bf16)v.x; b[1] = (bf16)v.y; b[2] = (bf16)v.z; b[3] = (bf16)v.w;
            *(bf16x4*)&Ls[r][c4 * 4] = b;
        }
        __syncthreads();
        #pragma unroll
        for (int p = 0; p < 2; ++p) {
            int id = t + p * 256;
            int crow = id >> 3, kc = id & 7;
            bf16x8 o;
            #pragma unroll
            for (int e = 0; e < 8; ++e) o[e] = Ls[kc * 8 + e][crow];
            *(bf16x8*)(WT + (size_t)(c0 + crow) * DMODEL + k0 + kc * 8) = o;
        }
    } else {
        const size_t base = (size_t)(bid - 576) * 4096;
        #pragma unroll
        for (int p = 0; p < 4; ++p) {
            size_t idx = base + (size_t)(t + p * 256) * 4;
            float4 v = *(const float4*)(x + idx);
            bf16x4 b; b[0] = (bf16)v.x; b[1] = (bf16)v.y; b[2] = (bf16)v.z; b[3] = (bf16)v.w;
            *(bf16x4*)(xb + idx) = b;
        }
    }
}

// -------------------- Kernel A: fused Q/K/V projections (r9) ----------
__global__ __launch_bounds__(256) void proj_kernel(
    const bf16* __restrict__ xb,
    const bf16* __restrict__ wqt, const bf16* __restrict__ wkt, const bf16* __restrict__ wvt,
    const float* __restrict__ b_q, const float* __restrict__ b_k, const float* __restrict__ b_v,
    bf16* __restrict__ qbuf, bf16* __restrict__ kbuf, bf16* __restrict__ vt)
{
    __shared__ bf16 As[128][72];
    __shared__ bf16 Bs[64][72];
    const int t = threadIdx.x;
    const int w = t >> 6, l = t & 63;
    const int lg = l >> 4, lr = l & 15;

    if (blockIdx.x < 768) {
        const int bn = blockIdx.x % 24;
        const int bm = blockIdx.x / 24;
        const int m0 = bm * 128;
        const int gn0 = bn * 64;
        const int sel = gn0 / DMODEL;        // 0=Q, 1=K
        const int c0 = gn0 % DMODEL;
        const bf16* WT = sel ? wkt : wqt;
        const float* bias = sel ? b_k : b_q;
        const float scale = sel ? 1.0f : QSCALE;

        f32x4 acc[2][4];
        #pragma unroll
        for (int i = 0; i < 2; i++)
            #pragma unroll
            for (int j = 0; j < 4; j++) acc[i][j] = (f32x4){0.f, 0.f, 0.f, 0.f};

        for (int kk = 0; kk < DMODEL; kk += 64) {
            #pragma unroll
            for (int p = 0; p < 4; ++p) {
                int id = t + p * 256;
                int row = id >> 3, ch = id & 7;
                *(bf16x8*)&As[row][ch * 8] =
                    *(const bf16x8*)(xb + (size_t)(m0 + row) * DMODEL + kk + ch * 8);
            }
            #pragma unroll
            for (int p = 0; p < 2; ++p) {
                int id = t + p * 256;
                int n = id >> 3, ch = id & 7;
                *(bf16x8*)&Bs[n][ch * 8] =
                    *(const bf16x8*)(WT + (size_t)(c0 + n) * DMODEL + kk + ch * 8);
            }
            __syncthreads();
            #pragma unroll
            for (int ks = 0; ks < 2; ++ks) {
                bf16x8 a[2], bfr[4];
                #pragma unroll
                for (int i = 0; i < 2; i++) a[i] = *(const bf16x8*)&As[w * 32 + i * 16 + lr][ks * 32 + lg * 8];
                #pragma unroll
                for (int j = 0; j < 4; j++) bfr[j] = *(const bf16x8*)&Bs[j * 16 + lr][ks * 32 + lg * 8];
                #pragma unroll
                for (int i = 0; i < 2; i++)
                    #pragma unroll
                    for (int j = 0; j < 4; j++)
                        acc[i][j] = __builtin_amdgcn_mfma_f32_16x16x32_bf16(a[i], bfr[j], acc[i][j], 0, 0, 0);
            }
            __syncthreads();
        }
        #pragma unroll
        for (int i = 0; i < 2; i++) {
            #pragma unroll
            for (int j = 0; j < 4; j++) {
                int c = c0 + j * 16 + lr;
                int h = c >> 6, d = c & 63;
                float bb = bias[c];
                #pragma unroll
                for (int r = 0; r < 4; r++) {
                    int m = m0 + w * 32 + i * 16 + lg * 4 + r;
                    float v = (acc[i][j][r] + bb) * scale;
                    if (sel == 0) {
                        qbuf[((size_t)h * L_SEQ + m) * DK + d] = (bf16)v;
                    } else {
                        size_t idx = (size_t)h * L_SEQ * DK + (size_t)(m >> 6) * 4096
                                   + (size_t)(m & 63) * 64 + (((d >> 3) ^ (m & 7)) << 3) + (d & 7);
                        kbuf[idx] = (bf16)v;
                    }
                }
            }
        }
    } else {
        const int bid = blockIdx.x - 768;
        const int bc = bid % 12;
        const int bmm = bid / 12;
        const int c0 = bc * 64;
        const int mm0 = bmm * 128;

        f32x4 acc[8];
        #pragma unroll
        for (int j = 0; j < 8; j++) acc[j] = (f32x4){0.f, 0.f, 0.f, 0.f};

        for (int kk = 0; kk < DMODEL; kk += 64) {
            #pragma unroll
            for (int p = 0; p < 4; ++p) {
                int id = t + p * 256;
                int row = id >> 3, ch = id & 7;
                *(bf16x8*)&As[row][ch * 8] =
                    *(const bf16x8*)(xb + (size_t)(mm0 + row) * DMODEL + kk + ch * 8);
            }
            #pragma unroll
            for (int p = 0; p < 2; ++p) {
                int id = t + p * 256;
                int n = id >> 3, ch = id & 7;
                *(bf16x8*)&Bs[n][ch * 8] =
                    *(const bf16x8*)(wvt + (size_t)(c0 + n) * DMODEL + kk + ch * 8);
            }
            __syncthreads();
            #pragma unroll
            for (int ks = 0; ks < 2; ++ks) {
                bf16x8 a = *(const bf16x8*)&Bs[w * 16 + lr][ks * 32 + lg * 8];
                #pragma unroll
                for (int j = 0; j < 8; j++) {
                    bf16x8 b = *(const bf16x8*)&As[j * 16 + lr][ks * 32 + lg * 8];
                    acc[j] = __builtin_amdgcn_mfma_f32_16x16x32_bf16(a, b, acc[j], 0, 0, 0);
                }
            }
            __syncthreads();
        }
        #pragma unroll
        for (int j = 0; j < 8; j++) {
            int m = mm0 + j * 16 + lr;
            #pragma unroll
            for (int r = 0; r < 4; r++) {
                int c = c0 + w * 16 + lg * 4 + r;
                float v = acc[j][r] + b_v[c];
                size_t idx = (size_t)(c >> 6) * DK * L_SEQ + (size_t)(m >> 6) * 4096
                           + (size_t)(c & 63) * 64 + ((((m >> 3) & 7) ^ (c & 7)) << 3) + (m & 7);
                vt[idx] = (bf16)v;
            }
        }
    }
}

// -------------------- Kernel B: causal flash attention (rotated pipeline) -------
// r9 parity-split structure + T15 rotation: S_next = QK(K_{t+1}) issues BEFORE
// softmax/PV of tile t, hiding QK latency under softmax VALU. K triple-buffered
// (prefetch distance stays 1 iter), V single-buffered via reg-staging (T14)
// with a post-PV barrier guarding the ds_write. LDS = 64KB (2 blocks/CU).
__global__ __launch_bounds__(512, 4) void attn_kernel(
    const bf16* __restrict__ qbuf, const bf16* __restrict__ kbuf,
    const bf16* __restrict__ vt, bf16* __restrict__ obuf)
{
    __shared__ __align__(16) char lds[65536];
    // Kbuf(g,b): (g*3+b)*8192, b=0..2  -> [0, 49152)
    // Vbuf(g):   49152 + g*8192        -> [49152, 65536)
    // merge alias (post-loop): mergeAcc @0 [256][21]f32, mergeM @22528 [256]f32

    const int bid = blockIdx.x;
    const int h  = bid % NH;
    const int qt = 63 - (bid / NH);       // LPT: heavy first
    const int q0 = qt * 64;
    const int nt = qt + 1;
    const int nit = (nt + 1) >> 1;

    const int t = threadIdx.x;
    const int w = t >> 6;
    const int g = w >> 2;                 // kv-parity group
    const int wg = w & 3;
    const int l = t & 63;
    const int lg = l >> 4, lr = l & 15;
    const int tg = t & 255;
    const int sw = (lr & 7) << 4;

    float* mergeAcc = (float*)lds;
    float* mergeM   = (float*)(lds + 22528);
    char* const Kb = lds + (size_t)g * 24576;
    char* const Vb = lds + 49152 + (size_t)g * 8192;

    const size_t qrow = (size_t)h * L_SEQ + q0 + wg * 16 + lr;
    const bf16x8 qa0 = *(const bf16x8*)(qbuf + qrow * DK + 0  + lg * 8);
    const bf16x8 qa1 = *(const bf16x8*)(qbuf + qrow * DK + 32 + lg * 8);

    bf16x8 ones;
    #pragma unroll
    for (int e = 0; e < 8; ++e) ones[e] = (bf16)1.0f;

    f32x4 acc[4];
    #pragma unroll
    for (int j = 0; j < 4; j++) acc[j] = (f32x4){0.f, 0.f, 0.f, 0.f};
    f32x4 acc_sum = (f32x4){0.f, 0.f, 0.f, 0.f};
    float run_m = -1e30f;

    const bf16* kb_base = kbuf + (size_t)h * L_SEQ * DK;
    const bf16* vt_base = vt + (size_t)h * DK * L_SEQ;

    bf16x8 vreg0, vreg1;
    // ---- prologue: K(T0)->Kb0, K(T1)->Kb1 (DMA); V(T0)->regs ----
    if (g < nt) {
        const bf16* kg = kb_base + (size_t)g * 4096;
        const bf16* vg = vt_base + (size_t)g * 4096;
        gload16(kg + tg * 8, Kb + tg * 16);
        gload16(kg + (tg + 256) * 8, Kb + (tg + 256) * 16);
        vreg0 = *(const bf16x8*)(vg + tg * 8);
        vreg1 = *(const bf16x8*)(vg + (tg + 256) * 8);
    }
    if (g + 2 < nt) {
        const bf16* kg = kb_base + (size_t)(g + 2) * 4096;
        gload16(kg + tg * 8, Kb + 8192 + tg * 16);
        gload16(kg + (tg + 256) * 8, Kb + 8192 + (tg + 256) * 16);
    }
    asm volatile("s_waitcnt vmcnt(0)" ::: "memory");
    __builtin_amdgcn_sched_barrier(0);
    __builtin_amdgcn_s_barrier();

    f32x4 S[4];
    #pragma unroll
    for (int j = 0; j < 4; j++) S[j] = (f32x4){0.f, 0.f, 0.f, 0.f};
    if (g < nt) {
        *(bf16x8*)(Vb + tg * 16) = vreg0;             // V(T0) -> LDS
        *(bf16x8*)(Vb + (tg + 256) * 16) = vreg1;
        #pragma unroll
        for (int dh = 0; dh < 2; ++dh) {              // S = QK(T0)
            const bf16x8 qa = dh ? qa1 : qa0;
            #pragma unroll
            for (int j = 0; j < 4; j++) {
                bf16x8 kv = *(const bf16x8*)(Kb + (j * 16 + lr) * 128 + ((dh * 64 + lg * 16) ^ sw));
                S[j] = __builtin_amdgcn_mfma_f32_16x16x32_bf16(kv, qa, S[j], 0, 0, 0);
            }
        }
    }

    for (int it = 0; it < nit; ++it) {
        const int cur = 2 * it + g;
        const bool active = (cur < nt);
        const int nxt = cur + 2, nx2 = cur + 4;
        // A: my prefetches landed + my ds_writes drained; sync all waves.
        asm volatile("s_waitcnt vmcnt(0) lgkmcnt(0)" ::: "memory");
        __builtin_amdgcn_sched_barrier(0);
        __builtin_amdgcn_s_barrier();
        // B: issue next V (to regs) and K(T+2) DMA -- fly during compute
        if (nxt < nt) {
            const bf16* vg = vt_base + (size_t)nxt * 4096;
            vreg0 = *(const bf16x8*)(vg + tg * 8);
            vreg1 = *(const bf16x8*)(vg + (tg + 256) * 8);
        }
        if (nx2 < nt) {
            const bf16* kg = kb_base + (size_t)nx2 * 4096;
            char* kl = Kb + (size_t)((it + 2) % 3) * 8192;
            gload16(kg + tg * 8, kl + tg * 16);
            gload16(kg + (tg + 256) * 8, kl + (tg + 256) * 16);
        }
        // C: S_next = QK(T_{it+1}) -- MFMA latency hides under D's VALU
        f32x4 Sn[4];
        #pragma unroll
        for (int j = 0; j < 4; j++) Sn[j] = (f32x4){0.f, 0.f, 0.f, 0.f};
        if (nxt < nt) {
            char* kn = Kb + (size_t)((it + 1) % 3) * 8192;
            __builtin_amdgcn_s_setprio(1);
            #pragma unroll
            for (int dh = 0; dh < 2; ++dh) {
                const bf16x8 qa = dh ? qa1 : qa0;
                #pragma unroll
                for (int j = 0; j < 4; j++) {
                    bf16x8 kv = *(const bf16x8*)(kn + (j * 16 + lr) * 128 + ((dh * 64 + lg * 16) ^ sw));
                    Sn[j] = __builtin_amdgcn_mfma_f32_16x16x32_bf16(kv, qa, Sn[j], 0, 0, 0);
                }
            }
            __builtin_amdgcn_s_setprio(0);
        }
        if (active) {
            // D: softmax of S (tile cur)
            if (cur == qt) {                  // causal mask on diagonal tile
                const int qoff = wg * 16 + lr;
                #pragma unroll
                for (int j = 0; j < 4; j++)
                    #pragma unroll
                    for (int r = 0; r < 4; r++)
                        if (j * 16 + lg * 4 + r > qoff) S[j][r] = -3e30f;
            }
            float m0 = fmaxf(fmaxf(S[0][0], S[0][1]), S[0][2]);
            float m1 = fmaxf(fmaxf(S[0][3], S[1][0]), S[1][1]);
            float m2 = fmaxf(fmaxf(S[1][2], S[1][3]), S[2][0]);
            float m3 = fmaxf(fmaxf(S[2][1], S[2][2]), S[2][3]);
            float m4 = fmaxf(fmaxf(S[3][0], S[3][1]), S[3][2]);
            float t1 = fmaxf(fmaxf(m0, m1), m2);
            float t2 = fmaxf(fmaxf(m3, m4), S[3][3]);
            float mx = fmaxf(t1, t2);
            mx = fmaxf(mx, __shfl_xor(mx, 16));
            mx = fmaxf(mx, __shfl_xor(mx, 32));
            if (!__all(mx <= run_m + DEFER_THR)) {
                const float nm = fmaxf(run_m, mx);
                const float scq = exp2f(run_m - nm);
                run_m = nm;
                float sc0 = __shfl(scq, lg * 4 + 0);
                float sc1 = __shfl(scq, lg * 4 + 1);
                float sc2 = __shfl(scq, lg * 4 + 2);
                float sc3 = __shfl(scq, lg * 4 + 3);
                #pragma unroll
                for (int jd = 0; jd < 4; jd++) {
                    acc[jd][0] *= sc0; acc[jd][1] *= sc1;
                    acc[jd][2] *= sc2; acc[jd][3] *= sc3;
                }
                acc_sum[0] *= sc0; acc_sum[1] *= sc1;
                acc_sum[2] *= sc2; acc_sum[3] *= sc3;
            }
            unsigned Wp[4][2];
            #pragma unroll
            for (int j = 0; j < 4; j++) {
                float e0 = exp2f(S[j][0] - run_m);
                float e1 = exp2f(S[j][1] - run_m);
                float e2 = exp2f(S[j][2] - run_m);
                float e3 = exp2f(S[j][3] - run_m);
                asm("v_cvt_pk_bf16_f32 %0, %1, %2" : "=v"(Wp[j][0]) : "v"(e0), "v"(e1));
                asm("v_cvt_pk_bf16_f32 %0, %1, %2" : "=v"(Wp[j][1]) : "v"(e2), "v"(e3));
            }
            // E: PV + row-sum (K=32 MFMA, in-register P repack)
            __builtin_amdgcn_s_setprio(1);
            #pragma unroll
            for (int dh = 0; dh < 2; ++dh) {
                unsigned x0 = Wp[2 * dh][0], y0 = Wp[2 * dh + 1][0];
                unsigned x1 = Wp[2 * dh][1], y1 = Wp[2 * dh + 1][1];
                asm("v_permlane32_swap_b32 %0, %1" : "+v"(x0), "+v"(y0));
                asm("v_permlane16_swap_b32 %0, %1" : "+v"(x0), "+v"(y0));
                asm("v_permlane32_swap_b32 %0, %1" : "+v"(x1), "+v"(y1));
                asm("v_permlane16_swap_b32 %0, %1" : "+v"(x1), "+v"(y1));
                union { unsigned u[4]; bf16x8 v; } pk;
                pk.u[0] = x0; pk.u[1] = x1; pk.u[2] = y0; pk.u[3] = y1;
                const bf16x8 pa = pk.v;
                acc_sum = __builtin_amdgcn_mfma_f32_16x16x32_bf16(pa, ones, acc_sum, 0, 0, 0);
                #pragma unroll
                for (int jd = 0; jd < 4; jd++) {
                    bf16x8 vb = *(const bf16x8*)(Vb + (jd * 16 + lr) * 128 + ((dh * 64 + lg * 16) ^ sw));
                    acc[jd] = __builtin_amdgcn_mfma_f32_16x16x32_bf16(pa, vb, acc[jd], 0, 0, 0);
                }
            }
            __builtin_amdgcn_s_setprio(0);
        }
        // F: all waves done reading Vb -> safe to overwrite
        __builtin_amdgcn_s_barrier();
        if (nxt < nt) {
            *(bf16x8*)(Vb + tg * 16) = vreg0;          // compiler waits vregs' vmcnt
            *(bf16x8*)(Vb + (tg + 256) * 16) = vreg1;
        }
        #pragma unroll
        for (int j = 0; j < 4; j++) S[j] = Sn[j];
    }

    // ---- merge group partials (group1 -> LDS, group0 combines & writes) ----
    __syncthreads();
    if (g == 1) {
        float* base = mergeAcc + (size_t)(wg * 64 + l) * 21;
        #pragma unroll
        for (int jd = 0; jd < 4; jd++)
            #pragma unroll
            for (int r = 0; r < 4; r++) base[jd * 4 + r] = acc[jd][r];
        #pragma unroll
        for (int r = 0; r < 4; r++) base[16 + r] = acc_sum[r];
        mergeM[wg * 64 + l] = run_m;
    }
    __syncthreads();
    if (g == 0) {
        const float* base = mergeAcc + (size_t)(wg * 64 + l) * 21;
        const float mB = mergeM[wg * 64 + l];
        const float mF = fmaxf(run_m, mB);
        const float sa = exp2f(run_m - mF);
        const float sb = exp2f(mB - mF);
        float a4[4], b4[4];
        #pragma unroll
        for (int r = 0; r < 4; r++) {
            a4[r] = __shfl(sa, lg * 4 + r);
            b4[r] = __shfl(sb, lg * 4 + r);
        }
        #pragma unroll
        for (int jd = 0; jd < 4; jd++) {
            #pragma unroll
            for (int r = 0; r < 4; r++) {
                float denom = acc_sum[r] * a4[r] + base[16 + r] * b4[r];
                float v = acc[jd][r] * a4[r] + base[jd * 4 + r] * b4[r];
                int m = q0 + wg * 16 + lg * 4 + r;
                obuf[(size_t)m * DMODEL + h * DK + jd * 16 + lr] = (bf16)(v / denom);
            }
        }
    }
}

// -------------------- Kernel C: output projection (r9) ---
__global__ __launch_bounds__(256) void out_proj_kernel(
    const bf16* __restrict__ obuf, const bf16* __restrict__ wot,
    const float* __restrict__ b_o, float* __restrict__ out)
{
    __shared__ bf16 As[128][72];
    __shared__ bf16 Bts[64][72];
    const int bn = blockIdx.x % 12;
    const int bm = blockIdx.x / 12;
    const int m0 = bm * 128, c0 = bn * 64;
    const int t = threadIdx.x;
    const int w = t >> 6, l = t & 63, lg = l >> 4, lr = l & 15;

    f32x4 acc[2][4];
    #pragma unroll
    for (int i = 0; i < 2; i++)
        #pragma unroll
        for (int j = 0; j < 4; j++) acc[i][j] = (f32x4){0.f, 0.f, 0.f, 0.f};

    for (int kk = 0; kk < DMODEL; kk += 64) {
        #pragma unroll
        for (int p = 0; p < 4; ++p) {
            int id = t + p * 256;
            int row = id >> 3, ch = id & 7;
            *(bf16x8*)&As[row][ch * 8] =
                *(const bf16x8*)(obuf + (size_t)(m0 + row) * DMODEL + kk + ch * 8);
        }
        #pragma unroll
        for (int p = 0; p < 2; ++p) {
            int id = t + p * 256;
            int n = id >> 3, ch = id & 7;
            *(bf16x8*)&Bts[n][ch * 8] =
                *(const bf16x8*)(wot + (size_t)(c0 + n) * DMODEL + kk + ch * 8);
        }
        __syncthreads();
        #pragma unroll
        for (int ks = 0; ks < 2; ++ks) {
            bf16x8 a[2], bfr[4];
            #pragma unroll
            for (int i = 0; i < 2; i++) a[i] = *(const bf16x8*)&As[w * 32 + i * 16 + lr][ks * 32 + lg * 8];
            #pragma unroll
            for (int j = 0; j < 4; j++) bfr[j] = *(const bf16x8*)&Bts[j * 16 + lr][ks * 32 + lg * 8];
            #pragma unroll
            for (int i = 0; i < 2; i++)
                #pragma unroll
                for (int j = 0; j < 4; j++)
                    acc[i][j] = __builtin_amdgcn_mfma_f32_16x16x32_bf16(a[i], bfr[j], acc[i][j], 0, 0, 0);
        }
        __syncthreads();
    }
    #pragma unroll
    for (int i = 0; i < 2; i++) {
        #pragma unroll
        for (int j = 0; j < 4; j++) {
            int c = c0 + j * 16 + lr;
            float bb = b_o[c];
            #pragma unroll
            for (int r = 0; r < 4; r++) {
                int m = m0 + w * 32 + i * 16 + lg * 4 + r;
                out[(size_t)m * DMODEL + c] = acc[i][j][r] + bb;
            }
        }
    }
}

extern "C" void kernel_launch(void* const* d_in, const int* in_sizes, int n_in,
                              void* d_out, int out_size, void* d_ws, size_t ws_size,
                              hipStream_t stream) {
    const float* x   = (const float*)d_in[0];
    const float* w_q = (const float*)d_in[1];
    const float* b_q = (const float*)d_in[2];
    const float* w_k = (const float*)d_in[3];
    const float* b_k = (const float*)d_in[4];
    const float* w_v = (const float*)d_in[5];
    const float* b_v = (const float*)d_in[6];
    const float* w_o = (const float*)d_in[7];
    const float* b_o = (const float*)d_in[8];
    float* out = (float*)d_out;

    char* ws = (char*)d_ws;
    const size_t SZ = (size_t)NH * L_SEQ * DK * sizeof(bf16);   // 6,291,456
    const size_t WTSZ = (size_t)DMODEL * DMODEL * sizeof(bf16); // 1,179,648
    bf16* qbuf = (bf16*)(ws);
    bf16* kbuf = (bf16*)(ws + SZ);
    bf16* vt   = (bf16*)(ws + 2 * SZ);
    bf16* obuf = (bf16*)(ws + 3 * SZ);
    bf16* xb   = (bf16*)(ws + 4 * SZ);
    bf16* wqt  = (bf16*)(ws + 5 * SZ);
    bf16* wkt  = (bf16*)(ws + 5 * SZ + WTSZ);
    bf16* wvt  = (bf16*)(ws + 5 * SZ + 2 * WTSZ);
    bf16* wot  = (bf16*)(ws + 5 * SZ + 3 * WTSZ);

    prep_kernel<<<dim3(1344), dim3(256), 0, stream>>>(x, w_q, w_k, w_v, w_o, xb, wqt, wkt, wvt, wot);
    proj_kernel<<<dim3(1152), dim3(256), 0, stream>>>(xb, wqt, wkt, wvt, b_q, b_k, b_v, qbuf, kbuf, vt);
    attn_kernel<<<dim3(768), dim3(512), 0, stream>>>(qbuf, kbuf, vt, obuf);
    out_proj_kernel<<<dim3(384), dim3(256), 0, stream>>>(obuf, wot, b_o, out);
}

// Round 15
// 115.011 us; speedup vs baseline: 1.1700x; 1.0448x over previous
//
#include <hip/hip_runtime.h>

#define L_SEQ 4096
#define DMODEL 768
#define NH 12
#define DK 64

typedef __bf16 bf16;
typedef __bf16 bf16x8 __attribute__((ext_vector_type(8)));
typedef __bf16 bf16x4 __attribute__((ext_vector_type(4)));
typedef float f32x4 __attribute__((ext_vector_type(4)));

#define QSCALE 0.1803368801111204f  /* 0.125 * log2(e): exp2 domain */
#define DEFER_THR 8.0f              /* defer-max threshold (exp2 domain): P <= 2^8 */

__device__ __forceinline__ void gload16(const void* g, void* l) {
    __builtin_amdgcn_global_load_lds(
        (const __attribute__((address_space(1))) unsigned int*)g,
        (__attribute__((address_space(3))) unsigned int*)l, 16, 0, 0);
}

// -------------------- Kernel 0: prep --------------------
__global__ __launch_bounds__(256) void prep_kernel(
    const float* __restrict__ x,
    const float* __restrict__ w_q, const float* __restrict__ w_k,
    const float* __restrict__ w_v, const float* __restrict__ w_o,
    bf16* __restrict__ xb, bf16* __restrict__ wqt, bf16* __restrict__ wkt,
    bf16* __restrict__ wvt, bf16* __restrict__ wot)
{
    const int bid = blockIdx.x;
    const int t = threadIdx.x;
    if (bid < 576) {
        __shared__ bf16 Ls[64][72];
        const int mat = bid / 144;
        const int tile = bid % 144;
        const int k0 = (tile / 12) * 64;
        const int c0 = (tile % 12) * 64;
        const float* W = mat == 0 ? w_q : mat == 1 ? w_k : mat == 2 ? w_v : w_o;
        bf16* WT = mat == 0 ? wqt : mat == 1 ? wkt : mat == 2 ? wvt : wot;
        #pragma unroll
        for (int p = 0; p < 4; ++p) {
            int id = t + p * 256;
            int r = id >> 4, c4 = id & 15;
            float4 v = *(const float4*)(W + (size_t)(k0 + r) * DMODEL + c0 + c4 * 4);
            bf16x4 b; b[0] = (bf16)v.x; b[1] = (bf16)v.y; b[2] = (bf16)v.z; b[3] = (bf16)v.w;
            *(bf16x4*)&Ls[r][c4 * 4] = b;
        }
        __syncthreads();
        #pragma unroll
        for (int p = 0; p < 2; ++p) {
            int id = t + p * 256;
            int crow = id >> 3, kc = id & 7;
            bf16x8 o;
            #pragma unroll
            for (int e = 0; e < 8; ++e) o[e] = Ls[kc * 8 + e][crow];
            *(bf16x8*)(WT + (size_t)(c0 + crow) * DMODEL + k0 + kc * 8) = o;
        }
    } else {
        const size_t base = (size_t)(bid - 576) * 4096;
        #pragma unroll
        for (int p = 0; p < 4; ++p) {
            size_t idx = base + (size_t)(t + p * 256) * 4;
            float4 v = *(const float4*)(x + idx);
            bf16x4 b; b[0] = (bf16)v.x; b[1] = (bf16)v.y; b[2] = (bf16)v.z; b[3] = (bf16)v.w;
            *(bf16x4*)(xb + idx) = b;
        }
    }
}

// -------------------- Kernel A: fused Q/K/V projections (bf16, BK=64) ----------
// K and V^T outputs are PRE-PERMUTED so attn's linear global_load_lds DMA
// reproduces the swizzled LDS image: within each 64-row tile,
//   slot (row, ch) holds data chunk (ch ^ (row&7)).
__global__ __launch_bounds__(256) void proj_kernel(
    const bf16* __restrict__ xb,
    const bf16* __restrict__ wqt, const bf16* __restrict__ wkt, const bf16* __restrict__ wvt,
    const float* __restrict__ b_q, const float* __restrict__ b_k, const float* __restrict__ b_v,
    bf16* __restrict__ qbuf, bf16* __restrict__ kbuf, bf16* __restrict__ vt)
{
    __shared__ bf16 As[128][72];
    __shared__ bf16 Bs[64][72];
    const int t = threadIdx.x;
    const int w = t >> 6, l = t & 63;
    const int lg = l >> 4, lr = l & 15;

    if (blockIdx.x < 768) {
        const int bn = blockIdx.x % 24;
        const int bm = blockIdx.x / 24;
        const int m0 = bm * 128;
        const int gn0 = bn * 64;
        const int sel = gn0 / DMODEL;        // 0=Q, 1=K
        const int c0 = gn0 % DMODEL;
        const bf16* WT = sel ? wkt : wqt;
        const float* bias = sel ? b_k : b_q;
        const float scale = sel ? 1.0f : QSCALE;

        f32x4 acc[2][4];
        #pragma unroll
        for (int i = 0; i < 2; i++)
            #pragma unroll
            for (int j = 0; j < 4; j++) acc[i][j] = (f32x4){0.f, 0.f, 0.f, 0.f};

        for (int kk = 0; kk < DMODEL; kk += 64) {
            #pragma unroll
            for (int p = 0; p < 4; ++p) {
                int id = t + p * 256;
                int row = id >> 3, ch = id & 7;
                *(bf16x8*)&As[row][ch * 8] =
                    *(const bf16x8*)(xb + (size_t)(m0 + row) * DMODEL + kk + ch * 8);
            }
            #pragma unroll
            for (int p = 0; p < 2; ++p) {
                int id = t + p * 256;
                int n = id >> 3, ch = id & 7;
                *(bf16x8*)&Bs[n][ch * 8] =
                    *(const bf16x8*)(WT + (size_t)(c0 + n) * DMODEL + kk + ch * 8);
            }
            __syncthreads();
            #pragma unroll
            for (int ks = 0; ks < 2; ++ks) {
                bf16x8 a[2], bfr[4];
                #pragma unroll
                for (int i = 0; i < 2; i++) a[i] = *(const bf16x8*)&As[w * 32 + i * 16 + lr][ks * 32 + lg * 8];
                #pragma unroll
                for (int j = 0; j < 4; j++) bfr[j] = *(const bf16x8*)&Bs[j * 16 + lr][ks * 32 + lg * 8];
                #pragma unroll
                for (int i = 0; i < 2; i++)
                    #pragma unroll
                    for (int j = 0; j < 4; j++)
                        acc[i][j] = __builtin_amdgcn_mfma_f32_16x16x32_bf16(a[i], bfr[j], acc[i][j], 0, 0, 0);
            }
            __syncthreads();
        }
        #pragma unroll
        for (int i = 0; i < 2; i++) {
            #pragma unroll
            for (int j = 0; j < 4; j++) {
                int c = c0 + j * 16 + lr;
                int h = c >> 6, d = c & 63;
                float bb = bias[c];
                #pragma unroll
                for (int r = 0; r < 4; r++) {
                    int m = m0 + w * 32 + i * 16 + lg * 4 + r;
                    float v = (acc[i][j][r] + bb) * scale;
                    if (sel == 0) {
                        qbuf[((size_t)h * L_SEQ + m) * DK + d] = (bf16)v;
                    } else {
                        // pre-permuted K: head h, tile m>>6, row m&63, chunk (d>>3)^(m&7)
                        size_t idx = (size_t)h * L_SEQ * DK + (size_t)(m >> 6) * 4096
                                   + (size_t)(m & 63) * 64 + (((d >> 3) ^ (m & 7)) << 3) + (d & 7);
                        kbuf[idx] = (bf16)v;
                    }
                }
            }
        }
    } else {
        const int bid = blockIdx.x - 768;
        const int bc = bid % 12;
        const int bmm = bid / 12;
        const int c0 = bc * 64;
        const int mm0 = bmm * 128;

        f32x4 acc[8];
        #pragma unroll
        for (int j = 0; j < 8; j++) acc[j] = (f32x4){0.f, 0.f, 0.f, 0.f};

        for (int kk = 0; kk < DMODEL; kk += 64) {
            #pragma unroll
            for (int p = 0; p < 4; ++p) {
                int id = t + p * 256;
                int row = id >> 3, ch = id & 7;
                *(bf16x8*)&As[row][ch * 8] =
                    *(const bf16x8*)(xb + (size_t)(mm0 + row) * DMODEL + kk + ch * 8);
            }
            #pragma unroll
            for (int p = 0; p < 2; ++p) {
                int id = t + p * 256;
                int n = id >> 3, ch = id & 7;
                *(bf16x8*)&Bs[n][ch * 8] =
                    *(const bf16x8*)(wvt + (size_t)(c0 + n) * DMODEL + kk + ch * 8);
            }
            __syncthreads();
            #pragma unroll
            for (int ks = 0; ks < 2; ++ks) {
                bf16x8 a = *(const bf16x8*)&Bs[w * 16 + lr][ks * 32 + lg * 8];
                #pragma unroll
                for (int j = 0; j < 8; j++) {
                    bf16x8 b = *(const bf16x8*)&As[j * 16 + lr][ks * 32 + lg * 8];
                    acc[j] = __builtin_amdgcn_mfma_f32_16x16x32_bf16(a, b, acc[j], 0, 0, 0);
                }
            }
            __syncthreads();
        }
        #pragma unroll
        for (int j = 0; j < 8; j++) {
            int m = mm0 + j * 16 + lr;
            #pragma unroll
            for (int r = 0; r < 4; r++) {
                int c = c0 + w * 16 + lg * 4 + r;
                float v = acc[j][r] + b_v[c];
                // pre-permuted V^T: head c>>6, tile m>>6, row c&63, chunk ((m>>3)&7)^(c&7)
                size_t idx = (size_t)(c >> 6) * DK * L_SEQ + (size_t)(m >> 6) * 4096
                           + (size_t)(c & 63) * 64 + ((((m >> 3) & 7) ^ (c & 7)) << 3) + (m & 7);
                vt[idx] = (bf16)v;
            }
        }
    }
}

// -------------------- Kernel B: causal flash attention --------------------
// 8 waves, parity-split kv groups; global_load_lds DMA staging, double-buffered,
// one raw barrier/iter. PV: K=32 MFMA with P repacked IN REGISTERS via
// cvt_pk + permlane32/16 swaps (no P LDS round-trip, no b64 reads).
__global__ __launch_bounds__(512) void attn_kernel(
    const bf16* __restrict__ qbuf, const bf16* __restrict__ kbuf,
    const bf16* __restrict__ vt, bf16* __restrict__ obuf)
{
    __shared__ __align__(16) char lds[65536];
    // K bufs: (g*2+b)*8192, b=0,1           @ [0, 32768)
    // V bufs: 32768 + (g*2+b)*8192          @ [32768, 65536)
    // merge alias (post-loop): mergeAcc @0 [256][21]f32, mergeM @22528 [256]f32

    const int bid = blockIdx.x;
    const int h  = bid % NH;
    const int qt = 63 - (bid / NH);       // LPT: heavy first
    const int q0 = qt * 64;
    const int nt = qt + 1;
    const int nit = (nt + 1) >> 1;

    const int t = threadIdx.x;
    const int w = t >> 6;
    const int g = w >> 2;
    const int wg = w & 3;
    const int l = t & 63;
    const int lg = l >> 4, lr = l & 15;
    const int tg = t & 255;
    const int sw = (lr & 7) << 4;

    float* mergeAcc = (float*)lds;
    float* mergeM   = (float*)(lds + 22528);

    const size_t qrow = (size_t)h * L_SEQ + q0 + wg * 16 + lr;
    const bf16x8 qa0 = *(const bf16x8*)(qbuf + qrow * DK + 0  + lg * 8);
    const bf16x8 qa1 = *(const bf16x8*)(qbuf + qrow * DK + 32 + lg * 8);

    bf16x8 ones;
    #pragma unroll
    for (int e = 0; e < 8; ++e) ones[e] = (bf16)1.0f;

    f32x4 acc[4];
    #pragma unroll
    for (int j = 0; j < 4; j++) acc[j] = (f32x4){0.f, 0.f, 0.f, 0.f};
    f32x4 acc_sum = (f32x4){0.f, 0.f, 0.f, 0.f};   // row sums, D-layout (q = lg*4+r)
    float run_m = -1e30f;                           // running max (q = lr)

    const bf16* kb_base = kbuf + (size_t)h * L_SEQ * DK;
    const bf16* vt_base = vt + (size_t)h * DK * L_SEQ;

    // prologue: DMA this group's first tile into buffer 0
    if (g < nt) {
        const bf16* kg = kb_base + (size_t)g * 4096;
        const bf16* vg = vt_base + (size_t)g * 4096;
        char* kl = lds + (size_t)(g << 1) * 8192;
        char* vl = lds + 32768 + (size_t)(g << 1) * 8192;
        #pragma unroll
        for (int p = 0; p < 2; ++p) {
            int id = tg + p * 256;
            gload16(kg + id * 8, kl + id * 16);
            gload16(vg + id * 8, vl + id * 16);
        }
    }

    for (int it = 0; it < nit; ++it) {
        const int cur = 2 * it + g;
        const bool active = (cur < nt);
        const int b = it & 1;
        // wait my DMA for tile `cur`, then barrier: all waves' shares landed
        // AND all waves done reading buf b^1.
        asm volatile("s_waitcnt vmcnt(0)" ::: "memory");
        __builtin_amdgcn_sched_barrier(0);
        __builtin_amdgcn_s_barrier();
        const int nxt = cur + 2;
        if (nxt < nt) {                   // DMA next tile; flies during compute
            const bf16* kg = kb_base + (size_t)nxt * 4096;
            const bf16* vg = vt_base + (size_t)nxt * 4096;
            char* kl = lds + (size_t)((g << 1) | (b ^ 1)) * 8192;
            char* vl = lds + 32768 + (size_t)((g << 1) | (b ^ 1)) * 8192;
            #pragma unroll
            for (int p = 0; p < 2; ++p) {
                int id = tg + p * 256;
                gload16(kg + id * 8, kl + id * 16);
                gload16(vg + id * 8, vl + id * 16);
            }
        }
        if (active) {
            char* Kbase = lds + (size_t)((g << 1) | b) * 8192;
            char* Vbase = lds + 32768 + (size_t)((g << 1) | b) * 8192;
            // S^T = K Q^T : s[j][r] -> kv-local = j*16 + lg*4 + r, q-local = lr
            f32x4 s[4];
            #pragma unroll
            for (int j = 0; j < 4; j++) s[j] = (f32x4){0.f, 0.f, 0.f, 0.f};
            __builtin_amdgcn_s_setprio(1);
            #pragma unroll
            for (int dh = 0; dh < 2; ++dh) {
                const bf16x8 qa = dh ? qa1 : qa0;
                #pragma unroll
                for (int j = 0; j < 4; j++) {
                    bf16x8 kb = *(const bf16x8*)(Kbase + (j * 16 + lr) * 128 + ((dh * 64 + lg * 16) ^ sw));
                    s[j] = __builtin_amdgcn_mfma_f32_16x16x32_bf16(kb, qa, s[j], 0, 0, 0);
                }
            }
            __builtin_amdgcn_s_setprio(0);
            if (cur == qt) {
                const int qoff = wg * 16 + lr;
                #pragma unroll
                for (int j = 0; j < 4; j++)
                    #pragma unroll
                    for (int r = 0; r < 4; r++)
                        if (j * 16 + lg * 4 + r > qoff) s[j][r] = -3e30f;
            }
            // tile max: max3 tree + 2 shfls
            float m0 = fmaxf(fmaxf(s[0][0], s[0][1]), s[0][2]);
            float m1 = fmaxf(fmaxf(s[0][3], s[1][0]), s[1][1]);
            float m2 = fmaxf(fmaxf(s[1][2], s[1][3]), s[2][0]);
            float m3 = fmaxf(fmaxf(s[2][1], s[2][2]), s[2][3]);
            float m4 = fmaxf(fmaxf(s[3][0], s[3][1]), s[3][2]);
            float t1 = fmaxf(fmaxf(m0, m1), m2);
            float t2 = fmaxf(fmaxf(m3, m4), s[3][3]);
            float mx = fmaxf(t1, t2);
            mx = fmaxf(mx, __shfl_xor(mx, 16));
            mx = fmaxf(mx, __shfl_xor(mx, 32));
            // defer-max rescale
            if (!__all(mx <= run_m + DEFER_THR)) {
                const float nm = fmaxf(run_m, mx);
                const float scq = exp2f(run_m - nm);
                run_m = nm;
                float sc0 = __shfl(scq, lg * 4 + 0);
                float sc1 = __shfl(scq, lg * 4 + 1);
                float sc2 = __shfl(scq, lg * 4 + 2);
                float sc3 = __shfl(scq, lg * 4 + 3);
                #pragma unroll
                for (int jd = 0; jd < 4; jd++) {
                    acc[jd][0] *= sc0; acc[jd][1] *= sc1;
                    acc[jd][2] *= sc2; acc[jd][3] *= sc3;
                }
                acc_sum[0] *= sc0; acc_sum[1] *= sc1;
                acc_sum[2] *= sc2; acc_sum[3] *= sc3;
            }
            // P = 2^(s - run_m) packed to words W[j][h]:
            //   W[j][h] @ lane(lg,lr) holds kv pair t = 8j + 2lg + h (q = lr)
            unsigned Wp[4][2];
            #pragma unroll
            for (int j = 0; j < 4; j++) {
                float e0 = exp2f(s[j][0] - run_m);
                float e1 = exp2f(s[j][1] - run_m);
                float e2 = exp2f(s[j][2] - run_m);
                float e3 = exp2f(s[j][3] - run_m);
                asm("v_cvt_pk_bf16_f32 %0, %1, %2" : "=v"(Wp[j][0]) : "v"(e0), "v"(e1));
                asm("v_cvt_pk_bf16_f32 %0, %1, %2" : "=v"(Wp[j][1]) : "v"(e2), "v"(e3));
            }
            // PV + row-sum, per 32-wide kv half: A-fragment word u needs pair
            // t = 16dh + 4lg + u. permlane32_swap then permlane16_swap on
            // (X=W[2dh][h], Y=W[2dh+1][h]) yield u=h (X'') and u=2+h (Y'').
            __builtin_amdgcn_s_setprio(1);
            #pragma unroll
            for (int dh = 0; dh < 2; ++dh) {
                unsigned x0 = Wp[2 * dh][0], y0 = Wp[2 * dh + 1][0];
                unsigned x1 = Wp[2 * dh][1], y1 = Wp[2 * dh + 1][1];
                asm("v_permlane32_swap_b32 %0, %1" : "+v"(x0), "+v"(y0));
                asm("v_permlane16_swap_b32 %0, %1" : "+v"(x0), "+v"(y0));
                asm("v_permlane32_swap_b32 %0, %1" : "+v"(x1), "+v"(y1));
                asm("v_permlane16_swap_b32 %0, %1" : "+v"(x1), "+v"(y1));
                union { unsigned u[4]; bf16x8 v; } pk;
                pk.u[0] = x0; pk.u[1] = x1; pk.u[2] = y0; pk.u[3] = y1;
                const bf16x8 pa = pk.v;
                acc_sum = __builtin_amdgcn_mfma_f32_16x16x32_bf16(pa, ones, acc_sum, 0, 0, 0);
                #pragma unroll
                for (int jd = 0; jd < 4; jd++) {
                    bf16x8 vb = *(const bf16x8*)(Vbase + (jd * 16 + lr) * 128 + ((dh * 64 + lg * 16) ^ sw));
                    acc[jd] = __builtin_amdgcn_mfma_f32_16x16x32_bf16(pa, vb, acc[jd], 0, 0, 0);
                }
            }
            __builtin_amdgcn_s_setprio(0);
        }
    }

    // ---- merge group partials (group1 -> LDS, group0 combines & writes) ----
    __syncthreads();
    if (g == 1) {
        float* base = mergeAcc + (size_t)(wg * 64 + l) * 21;
        #pragma unroll
        for (int jd = 0; jd < 4; jd++)
            #pragma unroll
            for (int r = 0; r < 4; r++) base[jd * 4 + r] = acc[jd][r];
        #pragma unroll
        for (int r = 0; r < 4; r++) base[16 + r] = acc_sum[r];
        mergeM[wg * 64 + l] = run_m;
    }
    __syncthreads();
    if (g == 0) {
        const float* base = mergeAcc + (size_t)(wg * 64 + l) * 21;
        const float mB = mergeM[wg * 64 + l];
        const float mF = fmaxf(run_m, mB);
        const float sa = exp2f(run_m - mF);
        const float sb = exp2f(mB - mF);
        float a4[4], b4[4];
        #pragma unroll
        for (int r = 0; r < 4; r++) {
            a4[r] = __shfl(sa, lg * 4 + r);
            b4[r] = __shfl(sb, lg * 4 + r);
        }
        #pragma unroll
        for (int jd = 0; jd < 4; jd++) {
            #pragma unroll
            for (int r = 0; r < 4; r++) {
                float denom = acc_sum[r] * a4[r] + base[16 + r] * b4[r];
                float v = acc[jd][r] * a4[r] + base[jd * 4 + r] * b4[r];
                int m = q0 + wg * 16 + lg * 4 + r;
                obuf[(size_t)m * DMODEL + h * DK + jd * 16 + lr] = (bf16)(v / denom);
            }
        }
    }
}

// -------------------- Kernel C: output projection (bf16 ops, BK=64, fp32 out) ---
__global__ __launch_bounds__(256) void out_proj_kernel(
    const bf16* __restrict__ obuf, const bf16* __restrict__ wot,
    const float* __restrict__ b_o, float* __restrict__ out)
{
    __shared__ bf16 As[128][72];
    __shared__ bf16 Bts[64][72];
    const int bn = blockIdx.x % 12;
    const int bm = blockIdx.x / 12;
    const int m0 = bm * 128, c0 = bn * 64;
    const int t = threadIdx.x;
    const int w = t >> 6, l = t & 63, lg = l >> 4, lr = l & 15;

    f32x4 acc[2][4];
    #pragma unroll
    for (int i = 0; i < 2; i++)
        #pragma unroll
        for (int j = 0; j < 4; j++) acc[i][j] = (f32x4){0.f, 0.f, 0.f, 0.f};

    for (int kk = 0; kk < DMODEL; kk += 64) {
        #pragma unroll
        for (int p = 0; p < 4; ++p) {
            int id = t + p * 256;
            int row = id >> 3, ch = id & 7;
            *(bf16x8*)&As[row][ch * 8] =
                *(const bf16x8*)(obuf + (size_t)(m0 + row) * DMODEL + kk + ch * 8);
        }
        #pragma unroll
        for (int p = 0; p < 2; ++p) {
            int id = t + p * 256;
            int n = id >> 3, ch = id & 7;
            *(bf16x8*)&Bts[n][ch * 8] =
                *(const bf16x8*)(wot + (size_t)(c0 + n) * DMODEL + kk + ch * 8);
        }
        __syncthreads();
        #pragma unroll
        for (int ks = 0; ks < 2; ++ks) {
            bf16x8 a[2], bfr[4];
            #pragma unroll
            for (int i = 0; i < 2; i++) a[i] = *(const bf16x8*)&As[w * 32 + i * 16 + lr][ks * 32 + lg * 8];
            #pragma unroll
            for (int j = 0; j < 4; j++) bfr[j] = *(const bf16x8*)&Bts[j * 16 + lr][ks * 32 + lg * 8];
            #pragma unroll
            for (int i = 0; i < 2; i++)
                #pragma unroll
                for (int j = 0; j < 4; j++)
                    acc[i][j] = __builtin_amdgcn_mfma_f32_16x16x32_bf16(a[i], bfr[j], acc[i][j], 0, 0, 0);
        }
        __syncthreads();
    }
    #pragma unroll
    for (int i = 0; i < 2; i++) {
        #pragma unroll
        for (int j = 0; j < 4; j++) {
            int c = c0 + j * 16 + lr;
            float bb = b_o[c];
            #pragma unroll
            for (int r = 0; r < 4; r++) {
                int m = m0 + w * 32 + i * 16 + lg * 4 + r;
                out[(size_t)m * DMODEL + c] = acc[i][j][r] + bb;
            }
        }
    }
}

extern "C" void kernel_launch(void* const* d_in, const int* in_sizes, int n_in,
                              void* d_out, int out_size, void* d_ws, size_t ws_size,
                              hipStream_t stream) {
    const float* x   = (const float*)d_in[0];
    const float* w_q = (const float*)d_in[1];
    const float* b_q = (const float*)d_in[2];
    const float* w_k = (const float*)d_in[3];
    const float* b_k = (const float*)d_in[4];
    const float* w_v = (const float*)d_in[5];
    const float* b_v = (const float*)d_in[6];
    const float* w_o = (const float*)d_in[7];
    const float* b_o = (const float*)d_in[8];
    float* out = (float*)d_out;

    char* ws = (char*)d_ws;
    const size_t SZ = (size_t)NH * L_SEQ * DK * sizeof(bf16);   // 6,291,456
    const size_t WTSZ = (size_t)DMODEL * DMODEL * sizeof(bf16); // 1,179,648
    bf16* qbuf = (bf16*)(ws);
    bf16* kbuf = (bf16*)(ws + SZ);
    bf16* vt   = (bf16*)(ws + 2 * SZ);
    bf16* obuf = (bf16*)(ws + 3 * SZ);
    bf16* xb   = (bf16*)(ws + 4 * SZ);
    bf16* wqt  = (bf16*)(ws + 5 * SZ);
    bf16* wkt  = (bf16*)(ws + 5 * SZ + WTSZ);
    bf16* wvt  = (bf16*)(ws + 5 * SZ + 2 * WTSZ);
    bf16* wot  = (bf16*)(ws + 5 * SZ + 3 * WTSZ);

    prep_kernel<<<dim3(1344), dim3(256), 0, stream>>>(x, w_q, w_k, w_v, w_o, xb, wqt, wkt, wvt, wot);
    proj_kernel<<<dim3(1152), dim3(256), 0, stream>>>(xb, wqt, wkt, wvt, b_q, b_k, b_v, qbuf, kbuf, vt);
    attn_kernel<<<dim3(768), dim3(512), 0, stream>>>(qbuf, kbuf, vt, obuf);
    out_proj_kernel<<<dim3(384), dim3(256), 0, stream>>>(obuf, wot, b_o, out);
}